// Round 2
// baseline (1332.623 us; speedup 1.0000x reference)
//
#include <hip/hip_runtime.h>
#include <hip/hip_bf16.h>
#include <math.h>

typedef unsigned char  u8;
typedef unsigned int   u32;
typedef __attribute__((ext_vector_type(8)))  int   int8v;
typedef __attribute__((ext_vector_type(16))) float f32x16;

#define IGNORE_INDEX (-100)

// ---------------- fp32 -> OCP e4m3 with explicit RNE ----------------
__device__ __forceinline__ u8 f32_to_e4m3(float f) {
    union { float f; u32 u; } v; v.f = f;
    u32 s  = (v.u >> 24) & 0x80u;
    u32 au = v.u & 0x7FFFFFFFu;
    float a = __uint_as_float(au);
    if (a >= 448.0f) return (u8)(s | 0x7E);          // clamp to max normal
    int e = (int)(au >> 23) - 127;
    if (e >= -6) {
        u32 m    = au & 0x7FFFFFu;
        u32 keep = m >> 20;
        u32 rest = m & 0xFFFFFu;
        keep += (rest > 0x80000u) || (rest == 0x80000u && (keep & 1u));
        u32 code = ((u32)(e + 7) << 3) + keep;        // mantissa carry bumps exponent
        if (code > 0x7E) code = 0x7E;
        return (u8)(s | code);
    } else {
        int q = (int)rintf(a * 512.0f);               // subnormal quantum 2^-9 (RNE)
        return (u8)(s | (u32)q);                      // q==8 lands on min-normal encoding
    }
}

// ---------------- fp32 -> fp8, packed into MFMA-fragment order ----------------
// P[panel][kc][s][lane][b], s = i2*4 + ks*2 + h; lane = khalf*32 + ln32
//   row = panel*128 + i2*32 + ln32
//   col = kc*128 + ks*64 + khalf*32 + h*16 + b
// Each fragment-half is 1024 CONTIGUOUS bytes -> staging is a linear copy.
__global__ __launch_bounds__(256) void cvt_pack_fp8(const float* __restrict__ in,
                                                    u8* __restrict__ out,
                                                    float scale, int H, int nRows) {
    __shared__ __align__(16) u8 lds[16384];
    const int kc    = blockIdx.x;
    const int panel = blockIdx.y;
    const int t     = threadIdx.x;

#pragma unroll
    for (int it = 0; it < 4; ++it) {
        int u  = it * 256 + t;          // 0..1023
        int r  = u >> 3;                // 0..127
        int cc = u & 7;                 // 16-col chunk within kc
        int row = panel * 128 + r;
        u8 tmp[16];
        if (row < nRows) {
            const float* src = in + (size_t)row * H + kc * 128 + cc * 16;
#pragma unroll
            for (int p = 0; p < 4; ++p) {
                float4 f = *(const float4*)(src + p * 4);
                tmp[p * 4 + 0] = f32_to_e4m3(f.x * scale);
                tmp[p * 4 + 1] = f32_to_e4m3(f.y * scale);
                tmp[p * 4 + 2] = f32_to_e4m3(f.z * scale);
                tmp[p * 4 + 3] = f32_to_e4m3(f.w * scale);
            }
        } else {
#pragma unroll
            for (int p = 0; p < 16; ++p) tmp[p] = 0;   // padded vocab rows -> 0.0
        }
        int i2 = r >> 5, ln32 = r & 31;
        int ks = cc >> 2, khalf = (cc >> 1) & 1, h = cc & 1;
        int s  = i2 * 4 + ks * 2 + h;
        int lane = khalf * 32 + ln32;
        *(int4*)(lds + s * 1024 + lane * 16) = *(const int4*)tmp;
    }
    __syncthreads();

    u8* dst = out + ((size_t)panel * gridDim.x + kc) * 16384;
    const int4* l4 = (const int4*)lds;
    int4* d4 = (int4*)dst;
#pragma unroll
    for (int p = 0; p < 4; ++p)
        d4[p * 256 + t] = l4[p * 256 + t];
}

// ---------------- fused MX-fp8 GEMM + online LSE partials ------------------
// 256x256 tile, K-step 64, 8 waves (2x4), each 128x64 via 4x2 mfma_scale
// 32x32x64. Operands staged global->LDS with global_load_lds (pre-packed
// fragments are contiguous -> linear copy, zero bank conflicts). Triple-
// buffered LDS so STAGE(t+2) never touches a buffer being read: exactly one
// raw s_barrier per K-step, with counted s_waitcnt vmcnt(4) (never 0 in the
// main loop) so 4 prefetch loads stay in flight across every barrier.
__device__ __forceinline__ void gl_lds16(const u8* g, u8* l) {
    __builtin_amdgcn_global_load_lds(
        (const __attribute__((address_space(1))) void*)g,
        (__attribute__((address_space(3))) void*)l, 16, 0, 0);
}

__global__ __launch_bounds__(512, 2) void gemm_lse_partial(
    const u8* __restrict__ Ap,      // packed [PM][KC][16][64][16] fp8 (x*8)
    const u8* __restrict__ Bp,      // packed [PV][KC][16][64][16] fp8 (W*16)
    float2* __restrict__ partials,  // [N][VT]  (m, sumexp)
    int KC, int V, int VT, int MT)
{
    __shared__ __align__(16) u8 sA3[3][16384];   // 3 x (2 panels x 8 chunks) x 1KB
    __shared__ __align__(16) u8 sB3[3][16384];
    __shared__ float2 red[256 * 4];

    const int tid   = threadIdx.x;
    const int w     = tid >> 6;          // 0..7
    const int lane  = tid & 63;
    const int wm    = w >> 2;            // 0..1 : 128-row half
    const int wn    = w & 3;             // 0..3 : 64-col quarter
    const int ln32  = lane & 31;
    const int khalf = lane >> 5;
    const int l16   = lane * 16;

    // XCD-aware bijective swizzle: consecutive swz ids (same XCD) walk m fast,
    // so the 16 blocks sharing one W panel live on one XCD's L2.
    const int nwg = MT * VT;
    int orig = blockIdx.x;
    int swz  = orig;
    if ((nwg & 7) == 0) { int cpx = nwg >> 3; swz = (orig & 7) * cpx + (orig >> 3); }
    const int bx = swz % MT;
    const int by = swz / MT;
    const int bx2 = bx * 2, by2 = by * 2;

    f32x16 acc[4][2];
#pragma unroll
    for (int i = 0; i < 4; ++i)
#pragma unroll
        for (int j = 0; j < 2; ++j)
#pragma unroll
            for (int r = 0; r < 16; ++r) acc[i][j][r] = 0.0f;

    const int scaleA = 0x7C7C7C7C;  // E8M0 124 = 2^-3 (undo x*8)
    const int scaleB = 0x7B7B7B7B;  // E8M0 123 = 2^-4 (undo W*16)

#define MFMA(av, bv, c) __builtin_amdgcn_mfma_scale_f32_32x32x64_f8f6f4(av, bv, c, 0, 0, 0, scaleA, 0, scaleB)

    // LDS chunk c (0..15): panel=c>>3, i2=(c>>1)&3, h=c&1  (at the K-step's ks)
#define STAGE(T_, B_) do { \
    int kc_ = (T_) >> 1, ks_ = (T_) & 1; \
    for (int k_ = 0; k_ < 2; ++k_) { \
        int cA_  = w * 2 + k_; \
        int pnl_ = cA_ >> 3, sub_ = cA_ & 7; \
        int s_   = (sub_ >> 1) * 4 + ks_ * 2 + (sub_ & 1); \
        gl_lds16(Ap + ((size_t)(bx2 + pnl_) * KC + kc_) * 16384 + s_ * 1024 + l16, \
                 &sA3[B_][cA_ * 1024]); \
        gl_lds16(Bp + ((size_t)(by2 + pnl_) * KC + kc_) * 16384 + s_ * 1024 + l16, \
                 &sB3[B_][cA_ * 1024]); \
    } } while (0)

#define LDF(dst, base, off) do { \
    int4 lo_ = *(const int4*)((base) + (off) + l16); \
    int4 hi_ = *(const int4*)((base) + (off) + 1024 + l16); \
    dst[0]=lo_.x; dst[1]=lo_.y; dst[2]=lo_.z; dst[3]=lo_.w; \
    dst[4]=hi_.x; dst[5]=hi_.y; dst[6]=hi_.z; dst[7]=hi_.w; } while (0)

    const int aOff = wm * 8192;                          // wave's A panel half
    const int bOff = (wn >> 1) * 8192 + (wn & 1) * 4096; // wave's B quarter

    const int T = KC * 2;              // K-steps of 64
    STAGE(0, 0);
    STAGE(1, 1);
    asm volatile("s_waitcnt vmcnt(4)\n\ts_barrier" ::: "memory");

    int cur = 0;
#pragma unroll 1
    for (int t = 0; t < T; ++t) {
        const u8* bA = &sA3[cur][0];
        const u8* bB = &sB3[cur][0];
        int8v a0, a1, a2, a3, b0v, b1v;
        LDF(a0, bA, aOff);           LDF(a1, bA, aOff + 2048);
        LDF(a2, bA, aOff + 4096);    LDF(a3, bA, aOff + 6144);
        LDF(b0v, bB, bOff);          LDF(b1v, bB, bOff + 2048);

        int nb = cur + 2; if (nb >= 3) nb -= 3;
        if (t + 2 < T) STAGE(t + 2, nb);     // prefetch flies under the MFMAs

        __builtin_amdgcn_s_setprio(1);
        acc[0][0] = MFMA(a0, b0v, acc[0][0]); acc[0][1] = MFMA(a0, b1v, acc[0][1]);
        acc[1][0] = MFMA(a1, b0v, acc[1][0]); acc[1][1] = MFMA(a1, b1v, acc[1][1]);
        acc[2][0] = MFMA(a2, b0v, acc[2][0]); acc[2][1] = MFMA(a2, b1v, acc[2][1]);
        acc[3][0] = MFMA(a3, b0v, acc[3][0]); acc[3][1] = MFMA(a3, b1v, acc[3][1]);
        __builtin_amdgcn_s_setprio(0);

        // publish buf (cur+1): its 4 loads (issued last iter) retired at vmcnt(4).
        if (t + 2 < T) asm volatile("s_waitcnt vmcnt(4) lgkmcnt(0)\n\ts_barrier" ::: "memory");
        else           asm volatile("s_waitcnt vmcnt(0) lgkmcnt(0)\n\ts_barrier" ::: "memory");
        cur = cur + 1; if (cur >= 3) cur -= 3;
    }

    // ---- online-softmax partial per row of the 256x256 tile ----
    // C/D 32x32 layout: col=lane&31, row=(reg&3)+8*(reg>>2)+4*(lane>>5).
    bool vj0 = (by * 256 + wn * 64 + ln32)      < V;
    bool vj1 = (by * 256 + wn * 64 + 32 + ln32) < V;

#pragma unroll
    for (int i2 = 0; i2 < 4; ++i2) {
#pragma unroll
        for (int r = 0; r < 16; ++r) {
            float x0 = vj0 ? acc[i2][0][r] : -INFINITY;
            float x1 = vj1 ? acc[i2][1][r] : -INFINITY;
            float m = fmaxf(x0, x1);
#pragma unroll
            for (int o = 1; o < 32; o <<= 1)
                m = fmaxf(m, __shfl_xor(m, o, 64));
            float s = 0.0f;
            if (vj0) s += __expf(acc[i2][0][r] - m);
            if (vj1) s += __expf(acc[i2][1][r] - m);
#pragma unroll
            for (int o = 1; o < 32; o <<= 1)
                s += __shfl_xor(s, o, 64);
            if (ln32 == 0) {
                int row = wm * 128 + i2 * 32 + (r & 3) + 8 * (r >> 2) + 4 * khalf;
                red[row * 4 + wn] = make_float2(m, s);
            }
        }
    }
    __syncthreads();

    if (tid < 256) {
        float m = -INFINITY, s = 0.0f;
#pragma unroll
        for (int q = 0; q < 4; ++q) {     // q=0 (wn=0) always finite -> no NaN
            float2 p = red[tid * 4 + q];
            float nm = fmaxf(m, p.x);
            s = s * __expf(m - nm) + p.y * __expf(p.x - nm);
            m = nm;
        }
        partials[(size_t)(bx * 256 + tid) * VT + by] = make_float2(m, s);
    }
#undef MFMA
#undef STAGE
#undef LDF
}

// ---------------- per-row: merge partials -> LSE, fp32 label dot ----------------
__global__ __launch_bounds__(256) void row_final(
    const float* __restrict__ x,      // [N][H] fp32
    const float* __restrict__ W,      // [V][H] fp32
    const int* __restrict__ y,        // [N]
    const float2* __restrict__ partials, // [N][VT]
    float* __restrict__ nll, float* __restrict__ valid,
    int H, int V, int VT)
{
    const int n = blockIdx.x;
    const int t = threadIdx.x;
    const int yn = y[n];
    const bool ok = (yn != IGNORE_INDEX);

    // label logit in full fp32
    float dsum = 0.0f;
    if (ok) {
        int cy = yn; if (cy < 0) cy = 0; if (cy >= V) cy = V - 1;
        const float4* xr = (const float4*)(x + (size_t)n * H);
        const float4* wr = (const float4*)(W + (size_t)cy * H);
        int nf4 = H >> 2;
        for (int i = t; i < nf4; i += 256) {
            float4 a = xr[i], b = wr[i];
            dsum += a.x * b.x + a.y * b.y + a.z * b.z + a.w * b.w;
        }
    }

    // merge this row's LSE partials
    float m = -INFINITY, s = 0.0f;
    const float2* pr = partials + (size_t)n * VT;
    for (int i = t; i < VT; i += 256) {
        float2 p = pr[i];
        float nm = fmaxf(m, p.x);
        s = s * __expf(m - nm) + p.y * __expf(p.x - nm);
        m = nm;
    }

    __shared__ float rm[256], rs[256], rd[256];
    rm[t] = m; rs[t] = s; rd[t] = dsum;
    __syncthreads();
    for (int o = 128; o > 0; o >>= 1) {
        if (t < o) {
            float m2 = rm[t + o], s2 = rs[t + o];
            float nm = fmaxf(rm[t], m2);
            rs[t] = rs[t] * __expf(rm[t] - nm) + s2 * __expf(m2 - nm);
            rm[t] = nm;
            rd[t] += rd[t + o];
        }
        __syncthreads();
    }
    if (t == 0) {
        float lse = rm[0] + __logf(rs[0]);
        nll[n]   = ok ? (lse - rd[0]) : 0.0f;
        valid[n] = ok ? 1.0f : 0.0f;
    }
}

// ---------------- final: loss = sum(nll) / max(sum(valid), 1) ----------------
__global__ __launch_bounds__(1024) void final_loss(
    const float* __restrict__ nll, const float* __restrict__ valid,
    float* __restrict__ out, int n)
{
    __shared__ float ss[1024], sv[1024];
    const int t = threadIdx.x;
    float a = 0.0f, b = 0.0f;
    for (int i = t; i < n; i += 1024) { a += nll[i]; b += valid[i]; }
    ss[t] = a; sv[t] = b;
    __syncthreads();
    for (int o = 512; o > 0; o >>= 1) {
        if (t < o) { ss[t] += ss[t + o]; sv[t] += sv[t + o]; }
        __syncthreads();
    }
    if (t == 0) out[0] = ss[0] / fmaxf(sv[0], 1.0f);
}

extern "C" void kernel_launch(void* const* d_in, const int* in_sizes, int n_in,
                              void* d_out, int out_size, void* d_ws, size_t ws_size,
                              hipStream_t stream) {
    const float* x = (const float*)d_in[0];
    const float* W = (const float*)d_in[1];
    const int*   y = (const int*)d_in[2];

    const long xsz = in_sizes[0];            // N*H
    const long wsz = in_sizes[1];            // V*H
    const int  N   = in_sizes[2];
    const int  H   = (int)(xsz / N);         // 2048
    const int  V   = (int)(wsz / H);         // 50257
    const int  VT  = (V + 255) / 256;        // 197  (256-col GEMM tiles)
    const int  PV  = VT * 2;                 // 394  (128-row packed panels)
    const int  MT  = N / 256;                // 16
    const int  PM  = N / 128;                // 32
    const int  KC  = H / 128;                // 16

    char* ws = (char*)d_ws;
    size_t off = 0;
    u8* Wp = (u8*)(ws + off); off += (size_t)PV * KC * 16384; off = (off + 255) & ~(size_t)255;
    u8* Xp = (u8*)(ws + off); off += (size_t)PM * KC * 16384; off = (off + 255) & ~(size_t)255;
    float2* partials = (float2*)(ws + off); off += (size_t)N * VT * sizeof(float2); off = (off + 255) & ~(size_t)255;
    float* nll   = (float*)(ws + off); off += (size_t)N * 4;
    float* valid = (float*)(ws + off); off += (size_t)N * 4;

    cvt_pack_fp8<<<dim3(KC, PV), 256, 0, stream>>>(W, Wp, 16.0f, H, V);
    cvt_pack_fp8<<<dim3(KC, PM), 256, 0, stream>>>(x, Xp, 8.0f, H, N);

    gemm_lse_partial<<<dim3(MT * VT), dim3(512), 0, stream>>>(Xp, Wp, partials, KC, V, VT, MT);

    row_final<<<N, 256, 0, stream>>>(x, W, y, partials, nll, valid, H, V, VT);
    final_loss<<<1, 1024, 0, stream>>>(nll, valid, (float*)d_out, N);
}

// Round 3
// 1284.846 us; speedup vs baseline: 1.0372x; 1.0372x over previous
//
#include <hip/hip_runtime.h>
#include <hip/hip_bf16.h>
#include <math.h>

typedef unsigned char  u8;
typedef unsigned int   u32;
typedef __attribute__((ext_vector_type(8)))  int   int8v;
typedef __attribute__((ext_vector_type(16))) float f32x16;

#define IGNORE_INDEX (-100)

// ---------------- fp32 -> OCP e4m3 with explicit RNE (fallback) ----------------
__device__ __forceinline__ u8 f32_to_e4m3(float f) {
    union { float f; u32 u; } v; v.f = f;
    u32 s  = (v.u >> 24) & 0x80u;
    u32 au = v.u & 0x7FFFFFFFu;
    float a = __uint_as_float(au);
    if (a >= 448.0f) return (u8)(s | 0x7E);          // clamp to max normal
    int e = (int)(au >> 23) - 127;
    if (e >= -6) {
        u32 m    = au & 0x7FFFFFu;
        u32 keep = m >> 20;
        u32 rest = m & 0xFFFFFu;
        keep += (rest > 0x80000u) || (rest == 0x80000u && (keep & 1u));
        u32 code = ((u32)(e + 7) << 3) + keep;        // mantissa carry bumps exponent
        if (code > 0x7E) code = 0x7E;
        return (u8)(s | code);
    } else {
        int q = (int)rintf(a * 512.0f);               // subnormal quantum 2^-9 (RNE)
        return (u8)(s | (u32)q);                      // q==8 lands on min-normal encoding
    }
}

// 4 floats -> 4 packed e4m3 bytes. HW path: v_cvt_pk_fp8_f32 (gfx950 = OCP
// e4m3, RNE; inputs here are always |x| << 448 so saturation never differs).
__device__ __forceinline__ u32 cvt4_e4m3(float4 f, float scale) {
#if __has_builtin(__builtin_amdgcn_cvt_pk_fp8_f32)
    int pk = 0;
    pk = __builtin_amdgcn_cvt_pk_fp8_f32(f.x * scale, f.y * scale, pk, false);
    pk = __builtin_amdgcn_cvt_pk_fp8_f32(f.z * scale, f.w * scale, pk, true);
    return (u32)pk;
#else
    u32 b0 = f32_to_e4m3(f.x * scale), b1 = f32_to_e4m3(f.y * scale);
    u32 b2 = f32_to_e4m3(f.z * scale), b3 = f32_to_e4m3(f.w * scale);
    return b0 | (b1 << 8) | (b2 << 16) | (b3 << 24);
#endif
}

// ---------------- fp32 -> fp8, packed into MFMA-fragment order ----------------
// P[panel][kc][s][lane][b], s = i2*4 + ks*2 + h; lane = khalf*32 + ln32
//   row = panel*128 + i2*32 + ln32
//   col = kc*128 + ks*64 + khalf*32 + h*16 + b
// Each fragment-half is 1024 CONTIGUOUS bytes -> the GEMM loads operands
// straight from global with coalesced dwordx4 per lane.
__global__ __launch_bounds__(256) void cvt_pack_fp8(const float* __restrict__ in,
                                                    u8* __restrict__ out,
                                                    float scale, int H, int nRows) {
    __shared__ __align__(16) u8 lds[16384];
    const int kc    = blockIdx.x;
    const int panel = blockIdx.y;
    const int t     = threadIdx.x;

#pragma unroll
    for (int it = 0; it < 4; ++it) {
        int u  = it * 256 + t;          // 0..1023
        int r  = u >> 3;                // 0..127
        int cc = u & 7;                 // 16-col chunk within kc
        int row = panel * 128 + r;
        u32 tmp[4];
        if (row < nRows) {
            const float* src = in + (size_t)row * H + kc * 128 + cc * 16;
#pragma unroll
            for (int p = 0; p < 4; ++p)
                tmp[p] = cvt4_e4m3(*(const float4*)(src + p * 4), scale);
        } else {
#pragma unroll
            for (int p = 0; p < 4; ++p) tmp[p] = 0;   // padded vocab rows -> 0.0
        }
        int i2 = r >> 5, ln32 = r & 31;
        int ks = cc >> 2, khalf = (cc >> 1) & 1, h = cc & 1;
        int s  = i2 * 4 + ks * 2 + h;
        int lane = khalf * 32 + ln32;
        *(int4*)(lds + s * 1024 + lane * 16) = *(const int4*)tmp;
    }
    __syncthreads();

    u8* dst = out + ((size_t)panel * gridDim.x + kc) * 16384;
    const int4* l4 = (const int4*)lds;
    int4* d4 = (int4*)dst;
#pragma unroll
    for (int p = 0; p < 4; ++p)
        d4[p * 256 + t] = l4[p * 256 + t];
}

// ---------------- fused MX-fp8 GEMM + online LSE partials, NO-LDS K-loop ----
// Block 256x128, 4 waves (wm 2 x wn 2), each wave 128x64 via 4x2 mfma_scale
// 32x32x64 => 1.5 KB of VMEM-return per MFMA (round-0's 2x2 was 2.0 KB).
// Free-run structure kept: zero barriers / zero LDS in the K-loop; waves
// stream pre-packed contiguous fragments global->VGPR (coalesced dwordx4),
// vmcnt scheduling overlaps loads of kc+1 with MFMAs of kc (unroll 2).
// Duplicate streams (each A frag read by 2 wn-waves, each B frag by 2
// wm-waves) are L1-adjacent on the same CU.
#define LD8(dst, base, off) { \
    int4 lo_ = *(const int4*)((base) + (off)); \
    int4 hi_ = *(const int4*)((base) + (off) + 1024); \
    dst[0]=lo_.x; dst[1]=lo_.y; dst[2]=lo_.z; dst[3]=lo_.w; \
    dst[4]=hi_.x; dst[5]=hi_.y; dst[6]=hi_.z; dst[7]=hi_.w; }

__global__ __launch_bounds__(256, 2) void gemm_lse_partial(
    const u8* __restrict__ Ap,      // packed [PM][KC][16][64][16] fp8 (x*8)
    const u8* __restrict__ Bp,      // packed [PV][KC][16][64][16] fp8 (W*16)
    float2* __restrict__ partials,  // [N][VT]  (m, sumexp)
    int KC, int V, int VT)
{
    __shared__ float2 red[256 * 2];

    const int tid  = threadIdx.x;
    const int w    = tid >> 6;
    const int lane = tid & 63;
    const int wm   = w >> 1, wn = w & 1;
    const int ln32 = lane & 31;
    const int khalf = lane >> 5;

    const int mBase  = blockIdx.x * 256;
    const int mPanel = blockIdx.x * 2 + wm;   // 128-row packed A panel
    const int vTile  = blockIdx.y;            // 128-col packed B panel
    const int vBase  = vTile * 128;

    f32x16 acc[4][2];
#pragma unroll
    for (int i = 0; i < 4; ++i)
#pragma unroll
        for (int j = 0; j < 2; ++j)
#pragma unroll
            for (int r = 0; r < 16; ++r) acc[i][j][r] = 0.0f;

    const int scaleA = 0x7C7C7C7C;  // E8M0 124 = 2^-3 (undo x*8)
    const int scaleB = 0x7B7B7B7B;  // E8M0 123 = 2^-4 (undo W*16)

    const u8* aPtr = Ap + ((size_t)mPanel * KC) * 16384 + lane * 16;
    const u8* bPtr = Bp + ((size_t)vTile  * KC) * 16384 + lane * 16;

    // fragment byte offsets: (i2*4 + ks*2)*1024, h-halves at +0/+1024 (LD8)
    const int b0O = (wn * 2    ) * 4096;     // B i2 = wn*2
    const int b1O = (wn * 2 + 1) * 4096;     // B i2 = wn*2+1

#define MFMA(av, bv, c) __builtin_amdgcn_mfma_scale_f32_32x32x64_f8f6f4(av, bv, c, 0, 0, 0, scaleA, 0, scaleB)

#pragma unroll 2
    for (int kc = 0; kc < KC; ++kc) {
        int8v a0, a1, a2, a3, b0v, b1v;
        // ---- ks = 0 ----
        LD8(a0, aPtr, 0);        LD8(a1, aPtr, 4096);
        LD8(a2, aPtr, 8192);     LD8(a3, aPtr, 12288);
        LD8(b0v, bPtr, b0O);     LD8(b1v, bPtr, b1O);
        acc[0][0] = MFMA(a0, b0v, acc[0][0]); acc[0][1] = MFMA(a0, b1v, acc[0][1]);
        acc[1][0] = MFMA(a1, b0v, acc[1][0]); acc[1][1] = MFMA(a1, b1v, acc[1][1]);
        acc[2][0] = MFMA(a2, b0v, acc[2][0]); acc[2][1] = MFMA(a2, b1v, acc[2][1]);
        acc[3][0] = MFMA(a3, b0v, acc[3][0]); acc[3][1] = MFMA(a3, b1v, acc[3][1]);
        // ---- ks = 1 ----
        LD8(a0, aPtr, 2048);         LD8(a1, aPtr, 4096 + 2048);
        LD8(a2, aPtr, 8192 + 2048);  LD8(a3, aPtr, 12288 + 2048);
        LD8(b0v, bPtr, b0O + 2048);  LD8(b1v, bPtr, b1O + 2048);
        acc[0][0] = MFMA(a0, b0v, acc[0][0]); acc[0][1] = MFMA(a0, b1v, acc[0][1]);
        acc[1][0] = MFMA(a1, b0v, acc[1][0]); acc[1][1] = MFMA(a1, b1v, acc[1][1]);
        acc[2][0] = MFMA(a2, b0v, acc[2][0]); acc[2][1] = MFMA(a2, b1v, acc[2][1]);
        acc[3][0] = MFMA(a3, b0v, acc[3][0]); acc[3][1] = MFMA(a3, b1v, acc[3][1]);

        aPtr += 16384; bPtr += 16384;
    }

    // ---- online-softmax partial per row of the 256x128 tile ----
    // C/D 32x32 layout (m74/m101, fmt-independent): col=lane&31,
    // row=(reg&3)+8*(reg>>2)+4*(lane>>5).
    bool vj0 = (vBase + wn * 64 + ln32)      < V;
    bool vj1 = (vBase + wn * 64 + 32 + ln32) < V;

#pragma unroll
    for (int i2 = 0; i2 < 4; ++i2) {
#pragma unroll
        for (int r = 0; r < 16; ++r) {
            float x0 = vj0 ? acc[i2][0][r] : -INFINITY;
            float x1 = vj1 ? acc[i2][1][r] : -INFINITY;
            float m = fmaxf(x0, x1);
#pragma unroll
            for (int o = 1; o < 32; o <<= 1)
                m = fmaxf(m, __shfl_xor(m, o, 64));
            float s = 0.0f;
            if (vj0) s += __expf(acc[i2][0][r] - m);
            if (vj1) s += __expf(acc[i2][1][r] - m);
#pragma unroll
            for (int o = 1; o < 32; o <<= 1)
                s += __shfl_xor(s, o, 64);
            if (ln32 == 0) {
                int row = wm * 128 + i2 * 32 + (r & 3) + 8 * (r >> 2) + 4 * khalf;
                red[row * 2 + wn] = make_float2(m, s);
            }
        }
    }
    __syncthreads();

    // 256 threads: one per row; merge the 2 column-half partials
    {
        float2 p0 = red[tid * 2 + 0];
        float2 p1 = red[tid * 2 + 1];
        float m = fmaxf(p0.x, p1.x);
        float s = p0.y * __expf(p0.x - m) + p1.y * __expf(p1.x - m);
        partials[(size_t)(mBase + tid) * VT + vTile] = make_float2(m, s);
    }
#undef MFMA
}

// ---------------- per-row: merge partials -> LSE, fp32 label dot ----------------
__global__ __launch_bounds__(256) void row_final(
    const float* __restrict__ x,      // [N][H] fp32
    const float* __restrict__ W,      // [V][H] fp32
    const int* __restrict__ y,        // [N]
    const float2* __restrict__ partials, // [N][VT]
    float* __restrict__ nll, float* __restrict__ valid,
    int H, int V, int VT)
{
    const int n = blockIdx.x;
    const int t = threadIdx.x;
    const int yn = y[n];
    const bool ok = (yn != IGNORE_INDEX);

    // label logit in full fp32
    float dsum = 0.0f;
    if (ok) {
        int cy = yn; if (cy < 0) cy = 0; if (cy >= V) cy = V - 1;
        const float4* xr = (const float4*)(x + (size_t)n * H);
        const float4* wr = (const float4*)(W + (size_t)cy * H);
        int nf4 = H >> 2;
        for (int i = t; i < nf4; i += 256) {
            float4 a = xr[i], b = wr[i];
            dsum += a.x * b.x + a.y * b.y + a.z * b.z + a.w * b.w;
        }
    }

    // merge this row's LSE partials
    float m = -INFINITY, s = 0.0f;
    const float2* pr = partials + (size_t)n * VT;
    for (int i = t; i < VT; i += 256) {
        float2 p = pr[i];
        float nm = fmaxf(m, p.x);
        s = s * __expf(m - nm) + p.y * __expf(p.x - nm);
        m = nm;
    }

    __shared__ float rm[256], rs[256], rd[256];
    rm[t] = m; rs[t] = s; rd[t] = dsum;
    __syncthreads();
    for (int o = 128; o > 0; o >>= 1) {
        if (t < o) {
            float m2 = rm[t + o], s2 = rs[t + o];
            float nm = fmaxf(rm[t], m2);
            rs[t] = rs[t] * __expf(rm[t] - nm) + s2 * __expf(m2 - nm);
            rm[t] = nm;
            rd[t] += rd[t + o];
        }
        __syncthreads();
    }
    if (t == 0) {
        float lse = rm[0] + __logf(rs[0]);
        nll[n]   = ok ? (lse - rd[0]) : 0.0f;
        valid[n] = ok ? 1.0f : 0.0f;
    }
}

// ---------------- final: loss = sum(nll) / max(sum(valid), 1) ----------------
__global__ __launch_bounds__(1024) void final_loss(
    const float* __restrict__ nll, const float* __restrict__ valid,
    float* __restrict__ out, int n)
{
    __shared__ float ss[1024], sv[1024];
    const int t = threadIdx.x;
    float a = 0.0f, b = 0.0f;
    for (int i = t; i < n; i += 1024) { a += nll[i]; b += valid[i]; }
    ss[t] = a; sv[t] = b;
    __syncthreads();
    for (int o = 512; o > 0; o >>= 1) {
        if (t < o) { ss[t] += ss[t + o]; sv[t] += sv[t + o]; }
        __syncthreads();
    }
    if (t == 0) out[0] = ss[0] / fmaxf(sv[0], 1.0f);
}

extern "C" void kernel_launch(void* const* d_in, const int* in_sizes, int n_in,
                              void* d_out, int out_size, void* d_ws, size_t ws_size,
                              hipStream_t stream) {
    const float* x = (const float*)d_in[0];
    const float* W = (const float*)d_in[1];
    const int*   y = (const int*)d_in[2];

    const long xsz = in_sizes[0];            // N*H
    const long wsz = in_sizes[1];            // V*H
    const int  N   = in_sizes[2];
    const int  H   = (int)(xsz / N);         // 2048
    const int  V   = (int)(wsz / H);         // 50257
    const int  VT  = (V + 127) / 128;        // 393  (128-col GEMM tiles / B panels)
    const int  MT  = N / 256;                // 16   (256-row GEMM tiles)
    const int  PM  = N / 128;                // 32   (128-row packed A panels)
    const int  KC  = H / 128;                // 16

    char* ws = (char*)d_ws;
    size_t off = 0;
    u8* Wp = (u8*)(ws + off); off += (size_t)VT * KC * 16384; off = (off + 255) & ~(size_t)255;
    u8* Xp = (u8*)(ws + off); off += (size_t)PM * KC * 16384; off = (off + 255) & ~(size_t)255;
    float2* partials = (float2*)(ws + off); off += (size_t)N * VT * sizeof(float2); off = (off + 255) & ~(size_t)255;
    float* nll   = (float*)(ws + off); off += (size_t)N * 4;
    float* valid = (float*)(ws + off); off += (size_t)N * 4;

    cvt_pack_fp8<<<dim3(KC, VT), 256, 0, stream>>>(W, Wp, 16.0f, H, V);
    cvt_pack_fp8<<<dim3(KC, PM), 256, 0, stream>>>(x, Xp, 8.0f, H, N);

    dim3 grid(MT, VT);   // mTile fast -> consecutive blocks share the W panel (L2/L3 reuse)
    gemm_lse_partial<<<grid, 256, 0, stream>>>(Xp, Wp, partials, KC, V, VT);

    row_final<<<N, 256, 0, stream>>>(x, W, y, partials, nll, valid, H, V, VT);
    final_loss<<<1, 1024, 0, stream>>>(nll, valid, (float*)d_out, N);
}